// Round 9
// baseline (243.579 us; speedup 1.0000x reference)
//
#include <hip/hip_runtime.h>
#include <stdint.h>

// CSSA: B=32, H=W=64, C=64, heads=4, hd=16, strip windows 64x8 -> 256 windows.
// Round 9 = Round 8 + fix: zero-init Vt's 8-elem/row pad. r8's NaN came from
// masked-weight x uninitialized-pad reads (0*inf=NaN). Structure: block=
// (window,head), 512 thr = 8 waves, wave=64 q; K + V^T in LDS; ones-MFMA
// denominator; depth-1 LDS frag pipeline; (512,6) -> no spill.
#define KSTR2 20    // K row: 16 ch + 4 pad (40 B)
#define VSTR  520   // Vt row: 512 tok + 8 pad

typedef __attribute__((ext_vector_type(4))) short          short4v;
typedef __attribute__((ext_vector_type(4))) float          f32x4;
typedef __attribute__((ext_vector_type(4))) unsigned short us4;
typedef __bf16 bf2_t __attribute__((ext_vector_type(2)));

__device__ __forceinline__ float bf2f(unsigned short u) {
    union { unsigned int i; float f; } x; x.i = ((unsigned int)u) << 16; return x.f;
}
__device__ __forceinline__ unsigned int pk2bf(float lo, float hi) {
#if __has_builtin(__builtin_amdgcn_cvt_pk_bf16_f32)
    union { bf2_t v; unsigned int u; } c;
    c.v = __builtin_amdgcn_cvt_pk_bf16_f32(lo, hi);     // 1 VALU op
    return c.u;
#else
    union { float f; unsigned int u; } a, b; a.f = lo; b.f = hi;
    return __builtin_amdgcn_perm(b.u + 0x8000u, a.u + 0x8000u, 0x07060302u);
#endif
}
__device__ __forceinline__ short4v pk4bf(float a, float b, float c, float d) {
    union { short4v s; unsigned int u[2]; } p;
    p.u[0] = pk2bf(a, b);
    p.u[1] = pk2bf(c, d);
    return p.s;
}

__global__ __launch_bounds__(512, 6)
void CSSA_69355131896243_kernel(const float* __restrict__ qkv,
                                const float* __restrict__ wconv,
                                const float* __restrict__ bconv,
                                float* __restrict__ out)
{
    __shared__ unsigned short Kl[512 * KSTR2];   // 20480 B  K[token][d] bf16
    __shared__ unsigned short Vt[16 * VSTR];     // 16640 B  V^T[d][token] bf16
    __shared__ float Wl[144];                    // this head's 16x9 conv weights
    __shared__ float Bl[16];

    const int tid  = threadIdx.x;
    const int wave = tid >> 6, lane = tid & 63, quad = lane >> 4, l15 = lane & 15;

    // bid -> (window, head): head-siblings 8 apart -> same XCD under round-robin
    // dispatch -> shared Q/K/V/out 256B lines merge in L2.
    const int bid = blockIdx.x;
    const int win = (bid & 7) * 32 + (bid >> 5);
    const int h   = (bid >> 3) & 3;
    const int b   = win >> 3, wx = win & 7;

    const size_t ONE  = (size_t)32 * 4096 * 64;
    const size_t base = ((size_t)b * 4096 + (size_t)wx * 8) * 64;
    const float* gQ = qkv + base;
    const float* gK = qkv + ONE + base;
    const float* gV = qkv + 2 * ONE + base;
    const int hc = h * 16;

    // ---- stage K (natural) + V^T as bf16; token-pair packed writes ----
    {
        const int c4 = tid & 3;          // 4-ch group within head
        const int tp = tid >> 2;         // token pair 0..127
        #pragma unroll
        for (int r = 0; r < 2; ++r) {
            const int t = r * 256 + tp * 2;     // even -> t,t+1 in same y-row
            const size_t g0 = (size_t)(t >> 3) * 4096 + (size_t)(t & 7) * 64 + hc + c4 * 4;
            f32x4 k0 = *(const f32x4*)(gK + g0);
            f32x4 k1 = *(const f32x4*)(gK + g0 + 64);
            f32x4 v0 = *(const f32x4*)(gV + g0);
            f32x4 v1 = *(const f32x4*)(gV + g0 + 64);
            union { us4 s; unsigned int u[2]; } kb0, kb1;
            kb0.u[0] = pk2bf(k0[0], k0[1]); kb0.u[1] = pk2bf(k0[2], k0[3]);
            kb1.u[0] = pk2bf(k1[0], k1[1]); kb1.u[1] = pk2bf(k1[2], k1[3]);
            *(us4*)(&Kl[t * KSTR2 + c4 * 4])       = kb0.s;
            *(us4*)(&Kl[(t + 1) * KSTR2 + c4 * 4]) = kb1.s;
            #pragma unroll
            for (int j = 0; j < 4; ++j)
                *(unsigned int*)(&Vt[(c4 * 4 + j) * VSTR + t]) = pk2bf(v0[j], v1[j]);
        }
    }
    // zero Vt pad (elems 512..519 of each row): epilogue halo taps read it with
    // weight 0 -- must be finite (0*inf=NaN was r8's bug).
    if (tid < 64) {
        const int r = tid >> 2, c = tid & 3;
        *(unsigned int*)(&Vt[r * VSTR + 512 + c * 2]) = 0u;
    }
    if (tid < 144) Wl[tid] = wconv[h * 144 + tid];
    if (tid < 16)  Bl[tid] = bconv[hc + tid];

    // ---- Q prefetch + pack (independent of LDS -> overlaps barrier wait) ----
    const float SCL = 0.25f * 1.44269504088896341f;   // scale*log2(e) folded in
    const int q0 = wave * 64;
    short4v qf[4];   // B[k=d=quad*4+i][n=q=l15]
    #pragma unroll
    for (int t = 0; t < 4; ++t) {
        const int q = q0 + t * 16 + l15;
        f32x4 qv = *(const f32x4*)(gQ + (size_t)(q >> 3) * 4096 + (size_t)(q & 7) * 64 + hc + quad * 4);
        qf[t] = pk4bf(qv[0] * SCL, qv[1] * SCL, qv[2] * SCL, qv[3] * SCL);
    }
    __syncthreads();

    short4v ones;   // bf16 1.0 x4: ones-A MFMA -> D rows = column sums of B
    {
        union { short4v s; unsigned short u[4]; } o;
        o.u[0] = 0x3F80; o.u[1] = 0x3F80; o.u[2] = 0x3F80; o.u[3] = 0x3F80;
        ones = o.s;
    }

    f32x4 acc[4], accl[4];
    #pragma unroll
    for (int t = 0; t < 4; ++t) { acc[t] = (f32x4)0.0f; accl[t] = (f32x4)0.0f; }

    // ---- main loop: 32 chunks x 16 keys; LDS frags pipelined depth 1 ----
    // K A-frag: A[m=key=l15][k=d=quad*4+i]; V A-frag: A[m=d=l15][k=key=quad*4+i]
    short4v kf = *(const short4v*)(&Kl[l15 * KSTR2 + quad * 4]);
    short4v vf = *(const short4v*)(&Vt[l15 * VSTR + quad * 4]);
    #pragma unroll 4
    for (int c = 0; c < 32; ++c) {
        const int cn = ((c + 1) & 31) * 16;          // last iter: harmless re-read
        short4v kfn = *(const short4v*)(&Kl[(cn + l15) * KSTR2 + quad * 4]);
        short4v vfn = *(const short4v*)(&Vt[l15 * VSTR + cn + quad * 4]);
        #pragma unroll
        for (int t = 0; t < 4; ++t) {
            // s^T[key][q]: C row=quad*4+j -> key, col=l15 -> q
            f32x4 s = __builtin_amdgcn_mfma_f32_16x16x16bf16_1k(kf, qf[t], (f32x4)0.0f, 0, 0, 0);
            const float p0 = __builtin_amdgcn_exp2f(s[0]);
            const float p1 = __builtin_amdgcn_exp2f(s[1]);
            const float p2 = __builtin_amdgcn_exp2f(s[2]);
            const float p3 = __builtin_amdgcn_exp2f(s[3]);
            const short4v pf = pk4bf(p0, p1, p2, p3);
            // P C-layout == K=16 B-frag layout -> PV straight from registers
            acc[t]  = __builtin_amdgcn_mfma_f32_16x16x16bf16_1k(vf,   pf, acc[t],  0, 0, 0);
            // denominator on the MFMA pipe: D[m][q] = sum_k P[k][q]
            accl[t] = __builtin_amdgcn_mfma_f32_16x16x16bf16_1k(ones, pf, accl[t], 0, 0, 0);
        }
        kf = kfn; vf = vfn;
    }

    float linv[4];
    #pragma unroll
    for (int t = 0; t < 4; ++t) linv[t] = __builtin_amdgcn_rcpf(accl[t][0]);

    // ---- epilogue: LePE from resident V^T, x-masks folded into weights ----
    const int xp = l15 & 7;                 // x = q&7 == l15&7 (t-independent)
    const bool xm = (xp != 0), xpb = (xp != 7);
    #pragma unroll
    for (int j = 0; j < 4; ++j) {
        const int d = quad * 4 + j;
        float wxm[9];
        #pragma unroll
        for (int o = 0; o < 3; ++o) {
            wxm[o * 3 + 0] = xm  ? Wl[d * 9 + o * 3 + 0] : 0.0f;
            wxm[o * 3 + 1] =       Wl[d * 9 + o * 3 + 1];
            wxm[o * 3 + 2] = xpb ? Wl[d * 9 + o * 3 + 2] : 0.0f;
        }
        const float bs = Bl[d];
        const unsigned short* Vrow = &Vt[d * VSTR];
        #pragma unroll
        for (int t = 0; t < 4; ++t) {
            const int q = q0 + t * 16 + l15;
            const int y = q >> 3;
            // halo taps: x-weight-mask or y-mask zeroes every OOB contribution;
            // pad reads (now zeroed) and cross-row reads are weight-masked.
            const float r0 = wxm[0] * bf2f(Vrow[q - 9]) + wxm[1] * bf2f(Vrow[q - 8]) + wxm[2] * bf2f(Vrow[q - 7]);
            const float r1 = wxm[3] * bf2f(Vrow[q - 1]) + wxm[4] * bf2f(Vrow[q])     + wxm[5] * bf2f(Vrow[q + 1]);
            const float r2 = wxm[6] * bf2f(Vrow[q + 7]) + wxm[7] * bf2f(Vrow[q + 8]) + wxm[8] * bf2f(Vrow[q + 9]);
            const float lep = bs + r1 + (y > 0 ? r0 : 0.0f) + (y < 63 ? r2 : 0.0f);
            acc[t][j] = acc[t][j] * linv[t] + lep;
        }
    }
    float* gO = out + base;
    #pragma unroll
    for (int t = 0; t < 4; ++t) {
        const int q = q0 + t * 16 + l15;
        *(f32x4*)(gO + (size_t)(q >> 3) * 4096 + (size_t)(q & 7) * 64 + hc + quad * 4) = acc[t];
    }
}

extern "C" void kernel_launch(void* const* d_in, const int* in_sizes, int n_in,
                              void* d_out, int out_size, void* d_ws, size_t ws_size,
                              hipStream_t stream) {
    const float* qkv   = (const float*)d_in[0];
    const float* wconv = (const float*)d_in[1];
    const float* bconv = (const float*)d_in[2];
    float* outp = (float*)d_out;
    hipLaunchKernelGGL(CSSA_69355131896243_kernel, dim3(1024), dim3(512), 0, stream,
                       qkv, wconv, bconv, outp);
}